// Round 13
// baseline (408.630 us; speedup 1.0000x reference)
//
#include <hip/hip_runtime.h>

#define BB 4
#define SS 2048
#define DDIM 512
#define HH 8
#define MTOK (BB*SS)   // 8192
#define BHN (BB*HH)    // 32

typedef _Float16 f16;
typedef __attribute__((ext_vector_type(8))) _Float16 half8;
typedef __attribute__((ext_vector_type(4))) _Float16 half4;
typedef __attribute__((ext_vector_type(4))) float float4v;
typedef __attribute__((ext_vector_type(4))) int int4v;

#define SCALE_L2E 0.180336880073616f   // 0.125 * log2(e)
#define L2E 1.44269504088896f
#define EBIAS 4.0f                     // cancels in softmax; f16 overflow headroom
#define MASKVAL -65504.0f              // f16 -max; exp2 -> 0

__device__ __forceinline__ float4v mfma_k32(half8 a, half8 b, float4v c) {
  return __builtin_amdgcn_mfma_f32_16x16x32_f16(a, b, c, 0, 0, 0);
}

__device__ __forceinline__ half8 cvt8(float4v a, float4v b) {
  half8 r;
  r[0] = (f16)a[0]; r[1] = (f16)a[1]; r[2] = (f16)a[2]; r[3] = (f16)a[3];
  r[4] = (f16)b[0]; r[5] = (f16)b[1]; r[6] = (f16)b[2]; r[7] = (f16)b[3];
  return r;
}

// ---------------- mask dtype detection ----------------
__global__ __launch_bounds__(256) void detect_mask_kernel(
    const unsigned int* __restrict__ m, unsigned int* __restrict__ flag) {
  unsigned int v = 0;
  const int base = blockIdx.x * 1024;
  for (int j = threadIdx.x; j < 1024; j += 256)
    if (m[base + j] > 1u) v = 1u;
  if (v) atomicOr(flag, 1u);
}

// ---------------- batched QKV projection ----------------
// z=0: Qp [tok][512] f16
// z=1: Kfrag[bh][tok>>4][dk>>5][(tok&15)+16*((dk>>3)&3)][dk&7]  (A-frag order)
// z=2: Vfrag[bh][tok>>5][dv>>4][(dv&15)+16*((tok>>2)&3)][((tok>>2)&4)+(tok&3)]
__global__ __launch_bounds__(256) void gemm_qkv(
    const float* __restrict__ inQ, const float* __restrict__ inK,
    const float* __restrict__ inV, const float* __restrict__ WQ,
    const float* __restrict__ WK, const float* __restrict__ WV,
    f16* __restrict__ Qp, f16* __restrict__ Kfrag, f16* __restrict__ Vfrag) {
  __shared__ f16 As[128][40];
  __shared__ f16 Bs[128][40];
  const int z = blockIdx.z;
  const float* A = (z == 0) ? inQ : (z == 1) ? inK : inV;
  const float* W = (z == 0) ? WQ : (z == 1) ? WK : WV;
  const int t = threadIdx.x;
  const int bm = blockIdx.x * 128;
  const int bn = blockIdx.y * 128;
  const int w = t >> 6, ln = t & 63;
  const int wr = w >> 1, wc = w & 1;
  const int lr = ln & 15, lg = ln >> 4;
  const int srow = t >> 1, scol = (t & 1) * 16;

  float4v acc[4][4] = {};

  for (int k0 = 0; k0 < 512; k0 += 32) {
    {
      const float* ap = A + (size_t)(bm + srow) * 512 + k0 + scol;
      float4v x0 = *(const float4v*)ap,       x1 = *(const float4v*)(ap + 4);
      float4v x2 = *(const float4v*)(ap + 8), x3 = *(const float4v*)(ap + 12);
      *(half8*)&As[srow][scol]     = cvt8(x0, x1);
      *(half8*)&As[srow][scol + 8] = cvt8(x2, x3);
    }
    {
      const float* wp = W + (size_t)(bn + srow) * 512 + k0 + scol;
      float4v x0 = *(const float4v*)wp,       x1 = *(const float4v*)(wp + 4);
      float4v x2 = *(const float4v*)(wp + 8), x3 = *(const float4v*)(wp + 12);
      *(half8*)&Bs[srow][scol]     = cvt8(x0, x1);
      *(half8*)&Bs[srow][scol + 8] = cvt8(x2, x3);
    }
    __syncthreads();
    half8 af[4], bf[4];
    #pragma unroll
    for (int m = 0; m < 4; m++) af[m] = *(const half8*)&As[wr * 64 + m * 16 + lr][lg * 8];
    #pragma unroll
    for (int n = 0; n < 4; n++) bf[n] = *(const half8*)&Bs[wc * 64 + n * 16 + lr][lg * 8];
    #pragma unroll
    for (int m = 0; m < 4; m++)
      #pragma unroll
      for (int n = 0; n < 4; n++) acc[m][n] = mfma_k32(af[m], bf[n], acc[m][n]);
    __syncthreads();
  }

  #pragma unroll
  for (int m = 0; m < 4; m++) {
    int row = bm + wr * 64 + m * 16 + lg * 4;
    #pragma unroll
    for (int n = 0; n < 4; n++) {
      int col = bn + wc * 64 + n * 16 + lr;
      int b_ = row >> 11, s_ = row & 2047, h_ = col >> 6, d_ = col & 63;
      if (z == 0) {
        #pragma unroll
        for (int r = 0; r < 4; r++)
          Qp[(size_t)(row + r) * 512 + col] = (f16)acc[m][n][r];
      } else if (z == 1) {
        #pragma unroll
        for (int r = 0; r < 4; r++) {
          int tok = s_ + r;
          Kfrag[((((size_t)(b_ * 8 + h_)) * 128 + (tok >> 4)) * 2 + (d_ >> 5)) * 512 +
                ((tok & 15) + 16 * ((d_ >> 3) & 3)) * 8 + (d_ & 7)] =
              (f16)acc[m][n][r];
        }
      } else {
        half4 ph;
        ph[0] = (f16)acc[m][n][0]; ph[1] = (f16)acc[m][n][1];
        ph[2] = (f16)acc[m][n][2]; ph[3] = (f16)acc[m][n][3];
        *(half4*)&Vfrag[((((size_t)(b_ * 8 + h_)) * 64 + (s_ >> 5)) * 4 + (d_ >> 4)) * 512 +
                        ((d_ & 15) + 16 * ((s_ >> 2) & 3)) * 8 + ((s_ >> 2) & 4)] = ph;
      }
    }
  }
}

// ---------------- fused attention + output GEMM ----------------
// Block = (b, 16 q-rows), 1024 thr = 16 waves (1 block/CU, LDS 147.5 KB).
// __launch_bounds__(1024, 4): 4 waves/SIMD -> 128 VGPR budget (the r12
// version's plain (1024) capped at 64 VGPR and spilled the whole loop).
// Heads sequential; wave w owns k-slice [w*128, w*128+128).  E in registers
// -> ONE QK^T + ONE exp.  Store/load order per head: sync2 -> next-head V
// load -> attn stores (loads OLDER than stores, so next BODY's vmcnt wait
// doesn't wait on store retirement).  Output GEMM fused in-block.
#define LOADT(dst, base, st) {                                  \
    const f16* p_ = (base) + (size_t)(st) * 2048;               \
    dst##0 = *(const half8*)(p_);                               \
    dst##1 = *(const half8*)(p_ + 512);                         \
    dst##2 = *(const half8*)(p_ + 1024);                        \
    dst##3 = *(const half8*)(p_ + 1536); }

__global__ __launch_bounds__(1024, 4) void attn_fused(
    const f16* __restrict__ Qp, const f16* __restrict__ Kfrag,
    const f16* __restrict__ Vfrag, const float* __restrict__ other,
    const unsigned char* __restrict__ mask8, const int* __restrict__ mask32,
    const unsigned int* __restrict__ flag, const float* __restrict__ WF,
    float* __restrict__ attn_out, float* __restrict__ Out) {
  __shared__ f16 othm[16][2056];      // masked, log2e-scaled f16  (65.8 KB)
  __shared__ float red[16][16];       // [wave][q] row-sum partials (1 KB)
  __shared__ float red2[16][16][66];  // [wave][q][dv] PV partials (67.6 KB)
  __shared__ f16 ctx_lds[16][520];    // [q][d=h*64+dv] context     (16.6 KB)

  const int t = threadIdx.x;
  const int bid = blockIdx.x;
  const int b = bid & 3;
  const int qblk = (bid >> 2) * 16;
  const int w = t >> 6, ln = t & 63;
  const int lr = ln & 15, lg = ln >> 4;
  const bool use8 = (*flag) != 0;

  // ---- stage other+mask once: thread -> (q = t>>6, 32 k at (t&63)*32) ----
  {
    const int q = t >> 6, k0 = (t & 63) * 32;
    const size_t base = ((size_t)b * SS + qblk + q) * SS + k0;
    const float* op = other + base;
    if (use8) {
      const unsigned char* mp = mask8 + base;
      #pragma unroll
      for (int g = 0; g < 4; g++) {
        unsigned int mw0 = *(const unsigned int*)(mp + g * 8);
        unsigned int mw1 = *(const unsigned int*)(mp + g * 8 + 4);
        float4v o0 = *(const float4v*)(op + g * 8);
        float4v o1 = *(const float4v*)(op + g * 8 + 4);
        float4v r0, r1;
        #pragma unroll
        for (int r = 0; r < 4; r++) {
          r0[r] = ((mw0 >> (8 * r)) & 0xffu) ? MASKVAL : fmaf(o0[r], L2E, -EBIAS);
          r1[r] = ((mw1 >> (8 * r)) & 0xffu) ? MASKVAL : fmaf(o1[r], L2E, -EBIAS);
        }
        *(half8*)&othm[q][k0 + g * 8] = cvt8(r0, r1);
      }
    } else {
      const int* mp = mask32 + base;
      #pragma unroll
      for (int g = 0; g < 4; g++) {
        int4v m0 = *(const int4v*)(mp + g * 8);
        int4v m1 = *(const int4v*)(mp + g * 8 + 4);
        float4v o0 = *(const float4v*)(op + g * 8);
        float4v o1 = *(const float4v*)(op + g * 8 + 4);
        float4v r0, r1;
        #pragma unroll
        for (int r = 0; r < 4; r++) {
          r0[r] = m0[r] ? MASKVAL : fmaf(o0[r], L2E, -EBIAS);
          r1[r] = m1[r] ? MASKVAL : fmaf(o1[r], L2E, -EBIAS);
        }
        *(half8*)&othm[q][k0 + g * 8] = cvt8(r0, r1);
      }
    }
  }
  __syncthreads();

  const int q_g = qblk + lr;
  const f16* kfb = Kfrag + (size_t)(b * 8) * 131072 + ln * 8;
  const f16* vfb = Vfrag + (size_t)(b * 8) * 131072 + ln * 8;
  const f16* qpp = Qp + ((size_t)b * SS + q_g) * 512 + lg * 8;

  half8 qf0 = *(const half8*)(qpp);
  half8 qf1 = *(const half8*)(qpp + 32);

  half8 kA0, kA1, kA2, kA3, kB0, kB1, kB2, kB3;
  half8 vf0, vf1, vf2, vf3;

  LOADT(kA, kfb, w * 4 + 0);
  LOADT(vf, vfb, w * 4 + 0);

  #define BODY(kf, edst, g) {                                             \
    float4v s0 = {}, s1 = {};                                             \
    s0 = mfma_k32(kf##0, qf0, s0);                                        \
    s0 = mfma_k32(kf##1, qf1, s0);                                        \
    s1 = mfma_k32(kf##2, qf0, s1);                                        \
    s1 = mfma_k32(kf##3, qf1, s1);                                        \
    const int kbase = w * 128 + (g) * 32;                                 \
    const half4 o40 = *(const half4*)&othm[lr][kbase + lg * 4];           \
    const half4 o41 = *(const half4*)&othm[lr][kbase + 16 + lg * 4];      \
    float4v ev0, ev1;                                                     \
    _Pragma("unroll")                                                     \
    for (int r = 0; r < 4; r++) {                                         \
      ev0[r] = exp2f(fmaf(s0[r], SCALE_L2E, (float)o40[r]));              \
      ev1[r] = exp2f(fmaf(s1[r], SCALE_L2E, (float)o41[r]));              \
    }                                                                     \
    rs += (ev0[0] + ev0[1]) + (ev0[2] + ev0[3]) +                         \
          (ev1[0] + ev1[1]) + (ev1[2] + ev1[3]);                          \
    edst = cvt8(ev0, ev1);                                                \
    cacc0 = mfma_k32(edst, vf0, cacc0);                                   \
    cacc1 = mfma_k32(edst, vf1, cacc1);                                   \
    cacc2 = mfma_k32(edst, vf2, cacc2);                                   \
    cacc3 = mfma_k32(edst, vf3, cacc3);                                   \
  }

  #define ASTORE(e, g) {                                                  \
    float4v av0, av1;                                                     \
    av0[0] = (float)e[0] * invl; av0[1] = (float)e[1] * invl;             \
    av0[2] = (float)e[2] * invl; av0[3] = (float)e[3] * invl;             \
    av1[0] = (float)e[4] * invl; av1[1] = (float)e[5] * invl;             \
    av1[2] = (float)e[6] * invl; av1[3] = (float)e[7] * invl;             \
    *(float4v*)(abase + (g) * 32 + lg * 4) = av0;                         \
    *(float4v*)(abase + (g) * 32 + 16 + lg * 4) = av1;                    \
  }

  for (int h = 0; h < 8; ++h) {
    const int bh = b * 8 + h;
    const f16* kfb_nx = (h < 7) ? kfb + 131072 : kfb;
    const f16* vfb_nx = (h < 7) ? vfb + 131072 : vfb;

    float rs = 0.f;
    float4v cacc0 = {}, cacc1 = {}, cacc2 = {}, cacc3 = {};
    half8 e0, e1, e2, e3;

    LOADT(kB, kfb, w * 4 + 1);
    BODY(kA, e0, 0);                        // vf(g=0) loaded before the stores

    LOADT(vf, vfb, w * 4 + 1);
    LOADT(kA, kfb, w * 4 + 2);
    BODY(kB, e1, 1);

    LOADT(vf, vfb, w * 4 + 2);
    LOADT(kB, kfb, w * 4 + 3);
    BODY(kA, e2, 2);

    LOADT(vf, vfb, w * 4 + 3);
    LOADT(kA, kfb_nx, w * 4 + 0);
    BODY(kB, e3, 3);

    // prefetch next head's Q (consumed after the barriers)
    const int hn = (h < 7) ? h + 1 : 7;
    half8 qn0 = *(const half8*)(qpp + hn * 64);
    half8 qn1 = *(const half8*)(qpp + hn * 64 + 32);

    // ---- reduction writes ----
    rs += __shfl_xor(rs, 16);
    rs += __shfl_xor(rs, 32);
    if (ln < 16) red[w][lr] = rs;
    #pragma unroll
    for (int r = 0; r < 4; r++) {
      red2[w][lg * 4 + r][0 * 16 + lr] = cacc0[r];
      red2[w][lg * 4 + r][1 * 16 + lr] = cacc1[r];
      red2[w][lg * 4 + r][2 * 16 + lr] = cacc2[r];
      red2[w][lg * 4 + r][3 * 16 + lr] = cacc3[r];
    }
    __syncthreads();  // sync1: partials visible

    // ---- read ALL sums into registers ----
    float lsum = 0.f;
    #pragma unroll
    for (int ww = 0; ww < 16; ww++) lsum += red[ww][lr];
    const float invl = 1.0f / lsum;
    float s16 = 0.f, l2 = 0.f;
    #pragma unroll
    for (int ww = 0; ww < 16; ww++) {
      s16 += red2[ww][w][ln];
      l2 += red[ww][w];
    }
    __syncthreads();  // sync2: red/red2 free for next head

    // next-head V(g=0) load FIRST (older than stores -> no store-wait)
    LOADT(vf, vfb_nx, w * 4 + 0);

    // stores issue after; retire under next head's compute
    float* abase = attn_out + ((size_t)bh * SS + q_g) * SS + w * 128;
    ASTORE(e0, 0);
    ASTORE(e1, 1);
    ASTORE(e2, 2);
    ASTORE(e3, 3);
    ctx_lds[w][h * 64 + ln] = (f16)(s16 / l2);

    qf0 = qn0;
    qf1 = qn1;
    kfb = kfb_nx;
    vfb = vfb_nx;
  }
  #undef BODY
  #undef ASTORE

  __syncthreads();  // ctx_lds complete

  // ---- fused output GEMM: out[q][n] = sum_d ctx[q][d] * WF[n][d] ----
  {
    const float* wrow0 = WF + (size_t)(w * 32 + lr) * 512;
    const float* wrow1 = WF + (size_t)(w * 32 + 16 + lr) * 512;
    float4v oacc0 = {}, oacc1 = {};
    #pragma unroll
    for (int ks = 0; ks < 16; ks++) {
      half8 af = *(const half8*)&ctx_lds[lr][ks * 32 + lg * 8];
      float4v w00 = *(const float4v*)(wrow0 + ks * 32 + lg * 8);
      float4v w01 = *(const float4v*)(wrow0 + ks * 32 + lg * 8 + 4);
      float4v w10 = *(const float4v*)(wrow1 + ks * 32 + lg * 8);
      float4v w11 = *(const float4v*)(wrow1 + ks * 32 + lg * 8 + 4);
      oacc0 = mfma_k32(af, cvt8(w00, w01), oacc0);
      oacc1 = mfma_k32(af, cvt8(w10, w11), oacc1);
    }
    #pragma unroll
    for (int r = 0; r < 4; r++) {
      float* ob = Out + ((size_t)b * SS + qblk + lg * 4 + r) * 512 + w * 32;
      ob[lr] = oacc0[r];
      ob[16 + lr] = oacc1[r];
    }
  }
}

extern "C" void kernel_launch(void* const* d_in, const int* in_sizes, int n_in,
                              void* d_out, int out_size, void* d_ws, size_t ws_size,
                              hipStream_t stream) {
  const float* inQ   = (const float*)d_in[0];
  const float* inK   = (const float*)d_in[1];
  const float* inV   = (const float*)d_in[2];
  const void*  mask  = d_in[3];
  const float* other = (const float*)d_in[4];
  const float* WQ    = (const float*)d_in[5];
  const float* WK    = (const float*)d_in[6];
  const float* WV    = (const float*)d_in[7];
  const float* WF    = (const float*)d_in[8];

  char* ws = (char*)d_ws;
  size_t off = 0;
  unsigned int* flag = (unsigned int*)(ws + off); off += 256;
  f16* Qp    = (f16*)(ws + off); off += (size_t)MTOK * 512 * 2;
  f16* Kfrag = (f16*)(ws + off); off += (size_t)MTOK * 512 * 2;
  f16* Vfrag = (f16*)(ws + off); off += (size_t)MTOK * 512 * 2;
  if (ws_size < off) return;

  float* outp  = (float*)d_out;
  float* attnp = outp + (size_t)MTOK * DDIM;

  hipMemsetAsync(flag, 0, 256, stream);
  detect_mask_kernel<<<64, 256, 0, stream>>>((const unsigned int*)mask, flag);

  gemm_qkv<<<dim3(64, 4, 3), 256, 0, stream>>>(inQ, inK, inV, WQ, WK, WV,
                                               Qp, Kfrag, Vfrag);

  attn_fused<<<512, 1024, 0, stream>>>(
      Qp, Kfrag, Vfrag, other, (const unsigned char*)mask, (const int*)mask,
      flag, WF, attnp, outp);
}

// Round 14
// 335.484 us; speedup vs baseline: 1.2180x; 1.2180x over previous
//
#include <hip/hip_runtime.h>

#define BB 4
#define SS 2048
#define DDIM 512
#define HH 8
#define MTOK (BB*SS)   // 8192
#define BHN (BB*HH)    // 32

typedef _Float16 f16;
typedef __attribute__((ext_vector_type(8))) _Float16 half8;
typedef __attribute__((ext_vector_type(4))) _Float16 half4;
typedef __attribute__((ext_vector_type(4))) float float4v;
typedef __attribute__((ext_vector_type(4))) int int4v;

#define SCALE_L2E 0.180336880073616f   // 0.125 * log2(e)
#define L2E 1.44269504088896f
#define EBIAS 4.0f                     // cancels in softmax; f16 overflow headroom
#define MASKVAL -65504.0f              // f16 -max; exp2 -> 0

__device__ __forceinline__ float4v mfma_k32(half8 a, half8 b, float4v c) {
  return __builtin_amdgcn_mfma_f32_16x16x32_f16(a, b, c, 0, 0, 0);
}

__device__ __forceinline__ half8 cvt8(float4v a, float4v b) {
  half8 r;
  r[0] = (f16)a[0]; r[1] = (f16)a[1]; r[2] = (f16)a[2]; r[3] = (f16)a[3];
  r[4] = (f16)b[0]; r[5] = (f16)b[1]; r[6] = (f16)b[2]; r[7] = (f16)b[3];
  return r;
}

// ---------------- mask dtype detection ----------------
__global__ __launch_bounds__(256) void detect_mask_kernel(
    const unsigned int* __restrict__ m, unsigned int* __restrict__ flag) {
  unsigned int v = 0;
  const int base = blockIdx.x * 1024;
  for (int j = threadIdx.x; j < 1024; j += 256)
    if (m[base + j] > 1u) v = 1u;
  if (v) atomicOr(flag, 1u);
}

// ---------------- batched QKV projection ----------------
// z=0: Qp [tok][512] f16
// z=1: Kfrag[bh][tok>>4][dk>>5][(tok&15)+16*((dk>>3)&3)][dk&7]  (A-frag order)
// z=2: Vfrag[bh][tok>>5][dv>>4][(dv&15)+16*((tok>>2)&3)][((tok>>2)&4)+(tok&3)]
__global__ __launch_bounds__(256) void gemm_qkv(
    const float* __restrict__ inQ, const float* __restrict__ inK,
    const float* __restrict__ inV, const float* __restrict__ WQ,
    const float* __restrict__ WK, const float* __restrict__ WV,
    f16* __restrict__ Qp, f16* __restrict__ Kfrag, f16* __restrict__ Vfrag) {
  __shared__ f16 As[128][40];
  __shared__ f16 Bs[128][40];
  const int z = blockIdx.z;
  const float* A = (z == 0) ? inQ : (z == 1) ? inK : inV;
  const float* W = (z == 0) ? WQ : (z == 1) ? WK : WV;
  const int t = threadIdx.x;
  const int bm = blockIdx.x * 128;
  const int bn = blockIdx.y * 128;
  const int w = t >> 6, ln = t & 63;
  const int wr = w >> 1, wc = w & 1;
  const int lr = ln & 15, lg = ln >> 4;
  const int srow = t >> 1, scol = (t & 1) * 16;

  float4v acc[4][4] = {};

  for (int k0 = 0; k0 < 512; k0 += 32) {
    {
      const float* ap = A + (size_t)(bm + srow) * 512 + k0 + scol;
      float4v x0 = *(const float4v*)ap,       x1 = *(const float4v*)(ap + 4);
      float4v x2 = *(const float4v*)(ap + 8), x3 = *(const float4v*)(ap + 12);
      *(half8*)&As[srow][scol]     = cvt8(x0, x1);
      *(half8*)&As[srow][scol + 8] = cvt8(x2, x3);
    }
    {
      const float* wp = W + (size_t)(bn + srow) * 512 + k0 + scol;
      float4v x0 = *(const float4v*)wp,       x1 = *(const float4v*)(wp + 4);
      float4v x2 = *(const float4v*)(wp + 8), x3 = *(const float4v*)(wp + 12);
      *(half8*)&Bs[srow][scol]     = cvt8(x0, x1);
      *(half8*)&Bs[srow][scol + 8] = cvt8(x2, x3);
    }
    __syncthreads();
    half8 af[4], bf[4];
    #pragma unroll
    for (int m = 0; m < 4; m++) af[m] = *(const half8*)&As[wr * 64 + m * 16 + lr][lg * 8];
    #pragma unroll
    for (int n = 0; n < 4; n++) bf[n] = *(const half8*)&Bs[wc * 64 + n * 16 + lr][lg * 8];
    #pragma unroll
    for (int m = 0; m < 4; m++)
      #pragma unroll
      for (int n = 0; n < 4; n++) acc[m][n] = mfma_k32(af[m], bf[n], acc[m][n]);
    __syncthreads();
  }

  #pragma unroll
  for (int m = 0; m < 4; m++) {
    int row = bm + wr * 64 + m * 16 + lg * 4;
    #pragma unroll
    for (int n = 0; n < 4; n++) {
      int col = bn + wc * 64 + n * 16 + lr;
      int b_ = row >> 11, s_ = row & 2047, h_ = col >> 6, d_ = col & 63;
      if (z == 0) {
        #pragma unroll
        for (int r = 0; r < 4; r++)
          Qp[(size_t)(row + r) * 512 + col] = (f16)acc[m][n][r];
      } else if (z == 1) {
        #pragma unroll
        for (int r = 0; r < 4; r++) {
          int tok = s_ + r;
          Kfrag[((((size_t)(b_ * 8 + h_)) * 128 + (tok >> 4)) * 2 + (d_ >> 5)) * 512 +
                ((tok & 15) + 16 * ((d_ >> 3) & 3)) * 8 + (d_ & 7)] =
              (f16)acc[m][n][r];
        }
      } else {
        half4 ph;
        ph[0] = (f16)acc[m][n][0]; ph[1] = (f16)acc[m][n][1];
        ph[2] = (f16)acc[m][n][2]; ph[3] = (f16)acc[m][n][3];
        *(half4*)&Vfrag[((((size_t)(b_ * 8 + h_)) * 64 + (s_ >> 5)) * 4 + (d_ >> 4)) * 512 +
                        ((d_ & 15) + 16 * ((s_ >> 2) & 3)) * 8 + ((s_ >> 2) & 4)] = ph;
      }
    }
  }
}

// ---------------- output GEMM: ctx (f16) x W_fc^T -> fp32 ----------------
__global__ __launch_bounds__(256) void gemm_out(const f16* __restrict__ ctx,
                                                const float* __restrict__ W,
                                                float* __restrict__ Out) {
  __shared__ f16 As[128][40];
  __shared__ f16 Bs[128][40];
  const int t = threadIdx.x;
  const int bm = blockIdx.x * 128;
  const int bn = blockIdx.y * 128;
  const int w = t >> 6, ln = t & 63;
  const int wr = w >> 1, wc = w & 1;
  const int lr = ln & 15, lg = ln >> 4;
  const int srow = t >> 1, scol = (t & 1) * 16;

  float4v acc[4][4] = {};

  for (int k0 = 0; k0 < 512; k0 += 32) {
    {
      const f16* ap = ctx + (size_t)(bm + srow) * 512 + k0 + scol;
      *(half8*)&As[srow][scol]     = *(const half8*)(ap);
      *(half8*)&As[srow][scol + 8] = *(const half8*)(ap + 8);
    }
    {
      const float* wp = W + (size_t)(bn + srow) * 512 + k0 + scol;
      float4v x0 = *(const float4v*)wp,       x1 = *(const float4v*)(wp + 4);
      float4v x2 = *(const float4v*)(wp + 8), x3 = *(const float4v*)(wp + 12);
      *(half8*)&Bs[srow][scol]     = cvt8(x0, x1);
      *(half8*)&Bs[srow][scol + 8] = cvt8(x2, x3);
    }
    __syncthreads();
    half8 af[4], bf[4];
    #pragma unroll
    for (int m = 0; m < 4; m++) af[m] = *(const half8*)&As[wr * 64 + m * 16 + lr][lg * 8];
    #pragma unroll
    for (int n = 0; n < 4; n++) bf[n] = *(const half8*)&Bs[wc * 64 + n * 16 + lr][lg * 8];
    #pragma unroll
    for (int m = 0; m < 4; m++)
      #pragma unroll
      for (int n = 0; n < 4; n++) acc[m][n] = mfma_k32(af[m], bf[n], acc[m][n]);
    __syncthreads();
  }

  #pragma unroll
  for (int m = 0; m < 4; m++) {
    int row = bm + wr * 64 + m * 16 + lg * 4;
    #pragma unroll
    for (int n = 0; n < 4; n++) {
      int col = bn + wc * 64 + n * 16 + lr;
      #pragma unroll
      for (int r = 0; r < 4; r++)
        Out[(size_t)(row + r) * 512 + col] = acc[m][n][r];
    }
  }
}

// ---------------- fused attention: head-sequential, single exp pass ----------------
// r11 structure.  KEY: amdgpu_waves_per_eu(4,4) pins min AND max waves/EU to
// 4 -> 128-VGPR budget (plain launch_bounds left the allocator targeting 8
// waves/EU -> 64 VGPR -> the whole K/V/E live set spilled to scratch; that
// was r12/r13's 380 us).  Block = (b, 16 q-rows), 1024 thr = 16 waves; heads
// sequential; wave w owns k-slice [w*128,w*128+128).  E in registers -> ONE
// QK^T + ONE exp.  other+mask staged once (66 KB LDS).  PV partials reduced
// via red2 (67.6 KB).  2 barriers/head.
#define LOADT(dst, base, st) {                                  \
    const f16* p_ = (base) + (size_t)(st) * 2048;               \
    dst##0 = *(const half8*)(p_);                               \
    dst##1 = *(const half8*)(p_ + 512);                         \
    dst##2 = *(const half8*)(p_ + 1024);                        \
    dst##3 = *(const half8*)(p_ + 1536); }

__global__ __launch_bounds__(1024)
__attribute__((amdgpu_waves_per_eu(4, 4)))
void attn_fused(
    const f16* __restrict__ Qp, const f16* __restrict__ Kfrag,
    const f16* __restrict__ Vfrag, const float* __restrict__ other,
    const unsigned char* __restrict__ mask8, const int* __restrict__ mask32,
    const unsigned int* __restrict__ flag, float* __restrict__ attn_out,
    f16* __restrict__ ctx) {
  __shared__ f16 othm[16][2056];      // masked, log2e-scaled f16  (65.8 KB)
  __shared__ float red[16][16];       // [wave][q] row-sum partials (1 KB)
  __shared__ float red2[16][16][66];  // [wave][q][dv] PV partials (67.6 KB)

  const int t = threadIdx.x;
  const int bid = blockIdx.x;
  const int b = bid & 3;
  const int qblk = (bid >> 2) * 16;
  const int w = t >> 6, ln = t & 63;
  const int lr = ln & 15, lg = ln >> 4;
  const bool use8 = (*flag) != 0;

  // ---- stage other+mask once: thread -> (q = t>>6, 32 k at (t&63)*32) ----
  {
    const int q = t >> 6, k0 = (t & 63) * 32;
    const size_t base = ((size_t)b * SS + qblk + q) * SS + k0;
    const float* op = other + base;
    if (use8) {
      const unsigned char* mp = mask8 + base;
      #pragma unroll
      for (int g = 0; g < 4; g++) {
        unsigned int mw0 = *(const unsigned int*)(mp + g * 8);
        unsigned int mw1 = *(const unsigned int*)(mp + g * 8 + 4);
        float4v o0 = *(const float4v*)(op + g * 8);
        float4v o1 = *(const float4v*)(op + g * 8 + 4);
        float4v r0, r1;
        #pragma unroll
        for (int r = 0; r < 4; r++) {
          r0[r] = ((mw0 >> (8 * r)) & 0xffu) ? MASKVAL : fmaf(o0[r], L2E, -EBIAS);
          r1[r] = ((mw1 >> (8 * r)) & 0xffu) ? MASKVAL : fmaf(o1[r], L2E, -EBIAS);
        }
        *(half8*)&othm[q][k0 + g * 8] = cvt8(r0, r1);
      }
    } else {
      const int* mp = mask32 + base;
      #pragma unroll
      for (int g = 0; g < 4; g++) {
        int4v m0 = *(const int4v*)(mp + g * 8);
        int4v m1 = *(const int4v*)(mp + g * 8 + 4);
        float4v o0 = *(const float4v*)(op + g * 8);
        float4v o1 = *(const float4v*)(op + g * 8 + 4);
        float4v r0, r1;
        #pragma unroll
        for (int r = 0; r < 4; r++) {
          r0[r] = m0[r] ? MASKVAL : fmaf(o0[r], L2E, -EBIAS);
          r1[r] = m1[r] ? MASKVAL : fmaf(o1[r], L2E, -EBIAS);
        }
        *(half8*)&othm[q][k0 + g * 8] = cvt8(r0, r1);
      }
    }
  }
  __syncthreads();

  const int q_g = qblk + lr;
  const f16* kfb = Kfrag + (size_t)(b * 8) * 131072 + ln * 8;
  const f16* vfb = Vfrag + (size_t)(b * 8) * 131072 + ln * 8;
  const f16* qpp = Qp + ((size_t)b * SS + q_g) * 512 + lg * 8;

  half8 qf0 = *(const half8*)(qpp);
  half8 qf1 = *(const half8*)(qpp + 32);

  half8 kA0, kA1, kA2, kA3, kB0, kB1, kB2, kB3;
  half8 vf0, vf1, vf2, vf3;

  LOADT(kA, kfb, w * 4 + 0);

  #define BODY(kf, edst, g) {                                             \
    float4v s0 = {}, s1 = {};                                             \
    s0 = mfma_k32(kf##0, qf0, s0);                                        \
    s0 = mfma_k32(kf##1, qf1, s0);                                        \
    s1 = mfma_k32(kf##2, qf0, s1);                                        \
    s1 = mfma_k32(kf##3, qf1, s1);                                        \
    const int kbase = w * 128 + (g) * 32;                                 \
    const half4 o40 = *(const half4*)&othm[lr][kbase + lg * 4];           \
    const half4 o41 = *(const half4*)&othm[lr][kbase + 16 + lg * 4];      \
    float4v ev0, ev1;                                                     \
    _Pragma("unroll")                                                     \
    for (int r = 0; r < 4; r++) {                                         \
      ev0[r] = exp2f(fmaf(s0[r], SCALE_L2E, (float)o40[r]));              \
      ev1[r] = exp2f(fmaf(s1[r], SCALE_L2E, (float)o41[r]));              \
    }                                                                     \
    rs += (ev0[0] + ev0[1]) + (ev0[2] + ev0[3]) +                         \
          (ev1[0] + ev1[1]) + (ev1[2] + ev1[3]);                          \
    edst = cvt8(ev0, ev1);                                                \
    cacc0 = mfma_k32(edst, vf0, cacc0);                                   \
    cacc1 = mfma_k32(edst, vf1, cacc1);                                   \
    cacc2 = mfma_k32(edst, vf2, cacc2);                                   \
    cacc3 = mfma_k32(edst, vf3, cacc3);                                   \
  }

  #define ASTORE(e, g) {                                                  \
    float4v av0, av1;                                                     \
    av0[0] = (float)e[0] * invl; av0[1] = (float)e[1] * invl;             \
    av0[2] = (float)e[2] * invl; av0[3] = (float)e[3] * invl;             \
    av1[0] = (float)e[4] * invl; av1[1] = (float)e[5] * invl;             \
    av1[2] = (float)e[6] * invl; av1[3] = (float)e[7] * invl;             \
    *(float4v*)(abase + (g) * 32 + lg * 4) = av0;                         \
    *(float4v*)(abase + (g) * 32 + 16 + lg * 4) = av1;                    \
  }

  for (int h = 0; h < 8; ++h) {
    const int bh = b * 8 + h;
    const f16* kfb_nx = (h < 7) ? kfb + 131072 : kfb;

    float rs = 0.f;
    float4v cacc0 = {}, cacc1 = {}, cacc2 = {}, cacc3 = {};
    half8 e0, e1, e2, e3;

    LOADT(vf, vfb, w * 4 + 0);
    LOADT(kB, kfb, w * 4 + 1);
    BODY(kA, e0, 0);

    LOADT(vf, vfb, w * 4 + 1);
    LOADT(kA, kfb, w * 4 + 2);
    BODY(kB, e1, 1);

    LOADT(vf, vfb, w * 4 + 2);
    LOADT(kB, kfb, w * 4 + 3);
    BODY(kA, e2, 2);

    LOADT(vf, vfb, w * 4 + 3);
    LOADT(kA, kfb_nx, w * 4 + 0);
    BODY(kB, e3, 3);

    // prefetch next head's Q (consumed after the barriers)
    const int hn = (h < 7) ? h + 1 : 7;
    half8 qn0 = *(const half8*)(qpp + hn * 64);
    half8 qn1 = *(const half8*)(qpp + hn * 64 + 32);

    // ---- cross-wave reductions ----
    rs += __shfl_xor(rs, 16);
    rs += __shfl_xor(rs, 32);
    if (ln < 16) red[w][lr] = rs;
    #pragma unroll
    for (int r = 0; r < 4; r++) {
      red2[w][lg * 4 + r][0 * 16 + lr] = cacc0[r];
      red2[w][lg * 4 + r][1 * 16 + lr] = cacc1[r];
      red2[w][lg * 4 + r][2 * 16 + lr] = cacc2[r];
      red2[w][lg * 4 + r][3 * 16 + lr] = cacc3[r];
    }
    __syncthreads();

    float lsum = 0.f;
    #pragma unroll
    for (int ww = 0; ww < 16; ww++) lsum += red[ww][lr];
    const float invl = 1.0f / lsum;

    float* abase = attn_out + ((size_t)bh * SS + q_g) * SS + w * 128;
    ASTORE(e0, 0);
    ASTORE(e1, 1);
    ASTORE(e2, 2);
    ASTORE(e3, 3);

    // ctx: wave w handles q-row w; lanes = dv
    {
      float s16 = 0.f, l2 = 0.f;
      #pragma unroll
      for (int ww = 0; ww < 16; ww++) {
        s16 += red2[ww][w][ln];
        l2 += red[ww][w];
      }
      ctx[((size_t)b * SS + qblk + w) * 512 + h * 64 + ln] = (f16)(s16 / l2);
    }
    __syncthreads();

    qf0 = qn0;
    qf1 = qn1;
    kfb = kfb_nx;
    vfb = (h < 7) ? vfb + 131072 : vfb;
  }
  #undef BODY
  #undef ASTORE
}

extern "C" void kernel_launch(void* const* d_in, const int* in_sizes, int n_in,
                              void* d_out, int out_size, void* d_ws, size_t ws_size,
                              hipStream_t stream) {
  const float* inQ   = (const float*)d_in[0];
  const float* inK   = (const float*)d_in[1];
  const float* inV   = (const float*)d_in[2];
  const void*  mask  = d_in[3];
  const float* other = (const float*)d_in[4];
  const float* WQ    = (const float*)d_in[5];
  const float* WK    = (const float*)d_in[6];
  const float* WV    = (const float*)d_in[7];
  const float* WF    = (const float*)d_in[8];

  char* ws = (char*)d_ws;
  size_t off = 0;
  unsigned int* flag = (unsigned int*)(ws + off); off += 256;
  f16* Qp    = (f16*)(ws + off); off += (size_t)MTOK * 512 * 2;
  f16* Kfrag = (f16*)(ws + off); off += (size_t)MTOK * 512 * 2;
  f16* Vfrag = (f16*)(ws + off); off += (size_t)MTOK * 512 * 2;
  f16* ctx   = (f16*)(ws + off); off += (size_t)MTOK * 512 * 2;
  if (ws_size < off) return;

  float* outp  = (float*)d_out;
  float* attnp = outp + (size_t)MTOK * DDIM;

  hipMemsetAsync(flag, 0, 256, stream);
  detect_mask_kernel<<<64, 256, 0, stream>>>((const unsigned int*)mask, flag);

  gemm_qkv<<<dim3(64, 4, 3), 256, 0, stream>>>(inQ, inK, inV, WQ, WK, WV,
                                               Qp, Kfrag, Vfrag);

  attn_fused<<<512, 1024, 0, stream>>>(
      Qp, Kfrag, Vfrag, other, (const unsigned char*)mask, (const int*)mask,
      flag, attnp, ctx);

  gemm_out<<<dim3(64, 4), 256, 0, stream>>>(ctx, WF, outp);
}